// Round 18
// baseline (91.137 us; speedup 1.0000x reference)
//
#include <hip/hip_runtime.h>
#include <hip/hip_bf16.h>

typedef __bf16 bf16_t;
typedef bf16_t bf16x8 __attribute__((ext_vector_type(8)));
typedef bf16_t bf16x4v __attribute__((ext_vector_type(4)));
typedef float f32x4 __attribute__((ext_vector_type(4)));
typedef float f32x16 __attribute__((ext_vector_type(16)));
typedef int i32x4 __attribute__((ext_vector_type(4)));

#define B_SZ 4
#define N_TOK 2048
#define DIM 512
#define H_N 8
#define DH 64
#define INNER 512
#define M_ROWS 8192
#define NQKV 1536
#define K_FOLD 0.18033688011112042f  // 0.125 * log2(e): softmax in exp2 domain

#define GLD_LDS16(gp, lp)                                          \
  __builtin_amdgcn_global_load_lds(                                \
      (const __attribute__((address_space(1))) void*)(gp),         \
      (__attribute__((address_space(3))) void*)(lp), 16, 0, 0)

// raw v_exp_f32: inputs bounded (|x| < ~14), no denormal concerns for softmax
__device__ __forceinline__ float fexp2(float x) {
#if __has_builtin(__builtin_amdgcn_exp2f)
  return __builtin_amdgcn_exp2f(x);
#else
  float r;
  asm volatile("v_exp_f32 %0, %1\n\ts_nop 1" : "=v"(r) : "v"(x));
  return r;
#endif
}

// pack two f32 -> one u32 holding (bf16(lo) | bf16(hi)<<16), RNE (same as cast)
__device__ __forceinline__ int cvtpk_bf16(float lo, float hi) {
  int r;
  asm("v_cvt_pk_bf16_f32 %0, %1, %2" : "=v"(r) : "v"(lo), "v"(hi));
  return r;
}

// swap a's upper-32-lane half with b's lower-32-lane half (in place)
__device__ __forceinline__ void permswap32(int& a, int& b) {
  asm volatile("v_permlane32_swap_b32 %0, %1" : "+v"(a), "+v"(b));
}

// ---------------- prep: W transposes only (X handled inside GEMM1) ----------------
// blocks [0,192): Wqkv 64x64 LDS-tiled transpose; [192,256): Wout
__global__ __launch_bounds__(256) void prep_kernel(
    const float* __restrict__ Wqkv, bf16_t* __restrict__ WqkvT,
    const float* __restrict__ Wout, bf16_t* __restrict__ WoutT) {
  __shared__ float t[64][65];   // pad-65: column reads are 2-way (free)
  int tb = blockIdx.x;
  const int tid = threadIdx.x;
  const float* src;
  bf16_t* dst;
  int C, r0, c0;
  if (tb < 192) {               // Wqkv: 512 x 1536, tiles 8 x 24
    src = Wqkv; dst = WqkvT; C = NQKV;
    r0 = (tb / 24) * 64; c0 = (tb % 24) * 64;
  } else {                      // Wout: 512 x 512, tiles 8 x 8
    tb -= 192;
    src = Wout; dst = WoutT; C = DIM;
    r0 = (tb >> 3) * 64; c0 = (tb & 7) * 64;
  }

  #pragma unroll
  for (int p = 0; p < 4; ++p) {
    int idx = p * 256 + tid;          // 0..1023 float4 slots
    int tr = idx >> 4, tc = (idx & 15) * 4;
    float4 v = *reinterpret_cast<const float4*>(&src[(size_t)(r0 + tr) * C + c0 + tc]);
    t[tr][tc] = v.x; t[tr][tc + 1] = v.y; t[tr][tc + 2] = v.z; t[tr][tc + 3] = v.w;
  }
  __syncthreads();
  #pragma unroll
  for (int p = 0; p < 2; ++p) {
    int idx = p * 256 + tid;          // 0..511 bf16x8 slots
    int d = idx >> 3, j8 = idx & 7;   // d = src col = dst row
    bf16x8 o;
    #pragma unroll
    for (int q = 0; q < 8; ++q) o[q] = (bf16_t)t[j8 * 8 + q][d];
    *reinterpret_cast<bf16x8*>(&dst[(size_t)(c0 + d) * 512 + r0 + j8 * 8]) = o;
  }
}

// ---------------- GEMM1: qkv projection ----------------
// A = X in f32 (reg-staged with inline cvt -- no separate conversion pass).
// Swapped-operand MFMA (R16-verified): D[row=qkv-col quad][col=token].
// q -> qb, k*K_FOLD -> kb: packed 8B quad stores. v: LDS-transpose epilogue ->
// coalesced 16B stores into V^T [B][H][64][N].
__global__ __launch_bounds__(256) void gemm_qkv_kernel(
    const float* __restrict__ Af, const bf16_t* __restrict__ Bt,
    bf16_t* __restrict__ qb, bf16_t* __restrict__ kb, bf16_t* __restrict__ vtb) {
  __shared__ __align__(16) char smem[36864];   // As(16K)+Bs(16K); v-epilogue T(33K)
  bf16_t* As = (bf16_t*)smem;
  bf16_t* Bs = (bf16_t*)(smem + 16384);

  const int tid = threadIdx.x;
  const int lane = tid & 63;
  const int wave = tid >> 6;
  const int g = lane >> 4, c = lane & 15;
  const int wm = (wave >> 1) * 64, wn = (wave & 1) * 64;
  const int m0 = blockIdx.x * 128, n0 = blockIdx.y * 128;

  f32x4 acc[4][4] = {};

  for (int k0 = 0; k0 < DIM; k0 += 64) {
    __syncthreads();
    // B staging via global_load_lds (bf16, swizzled source)
    #pragma unroll
    for (int i = 0; i < 4; ++i) {
      int blk = i * 256 + tid;
      int row = blk >> 3;
      int cb = (blk & 7) ^ (row & 7);
      int base = (i * 256 + wave * 64) * 8;
      GLD_LDS16(Bt + (size_t)(n0 + row) * DIM + k0 + cb * 8, &Bs[base]);
    }
    // A staging: f32 global reads + cvt_pk + swizzled ds_write_b128
    #pragma unroll
    for (int i = 0; i < 4; ++i) {
      int blk = i * 256 + tid;          // bf16 16B-block id 0..1023
      int row = blk >> 3, lb = blk & 7;
      const float* sp = &Af[(size_t)(m0 + row) * DIM + k0 + lb * 8];
      float4 f0 = *reinterpret_cast<const float4*>(sp);
      float4 f1 = *reinterpret_cast<const float4*>(sp + 4);
      i32x4 w;
      w.x = cvtpk_bf16(f0.x, f0.y);
      w.y = cvtpk_bf16(f0.z, f0.w);
      w.z = cvtpk_bf16(f1.x, f1.y);
      w.w = cvtpk_bf16(f1.z, f1.w);
      *reinterpret_cast<i32x4*>(&As[row * 64 + ((lb ^ (row & 7)) * 8)]) = w;
    }
    __syncthreads();
    __builtin_amdgcn_s_setprio(1);
    #pragma unroll
    for (int ks = 0; ks < 2; ++ks) {
      bf16x8 af[4], bfr[4];
      #pragma unroll
      for (int i = 0; i < 4; ++i) {
        af[i] = *reinterpret_cast<const bf16x8*>(
            &As[(wm + i * 16 + c) * 64 + (((ks * 4 + g) ^ (c & 7)) * 8)]);
        bfr[i] = *reinterpret_cast<const bf16x8*>(
            &Bs[(wn + i * 16 + c) * 64 + (((ks * 4 + g) ^ (c & 7)) * 8)]);
      }
      // swapped: A-op = W fragment (n-space), B-op = X fragment (token-space)
      #pragma unroll
      for (int mi = 0; mi < 4; ++mi)
        #pragma unroll
        for (int ni = 0; ni < 4; ++ni)
          acc[mi][ni] = __builtin_amdgcn_mfma_f32_16x16x32_bf16(
              bfr[ni], af[mi], acc[mi][ni], 0, 0, 0);
    }
    __builtin_amdgcn_s_setprio(0);
  }

  if (n0 < 1024) {
    // q/k: reg quad spans 4 consecutive qkv cols -> packed 8B stores (R16-verified)
    #pragma unroll
    for (int mi = 0; mi < 4; ++mi) {
      #pragma unroll
      for (int ni = 0; ni < 4; ++ni) {
        int rowg = m0 + wm + mi * 16 + c;            // token
        int colg0 = n0 + wn + ni * 16 + g * 4;       // qkv col quad base
        int s = colg0 >> 9;
        int hh = (colg0 >> 6) & 7, dd = colg0 & 63;
        int bb = rowg >> 11, nn = rowg & 2047;
        float sc = (s == 1) ? K_FOLD : 1.0f;
        bf16_t* dst = (s == 0) ? qb : kb;
        bf16x4v pk;
        pk.x = (bf16_t)(acc[mi][ni][0] * sc);
        pk.y = (bf16_t)(acc[mi][ni][1] * sc);
        pk.z = (bf16_t)(acc[mi][ni][2] * sc);
        pk.w = (bf16_t)(acc[mi][ni][3] * sc);
        *reinterpret_cast<bf16x4v*>(
            &dst[(((size_t)(bb * H_N + hh)) * N_TOK + nn) * DH + dd]) = pk;
      }
    }
  } else {
    // v: LDS transpose -> coalesced V^T stores. T[128 dd][132 pad] aliases As/Bs.
    __syncthreads();   // all waves done reading As/Bs
    bf16_t* T = (bf16_t*)smem;
    #pragma unroll
    for (int mi = 0; mi < 4; ++mi)
      #pragma unroll
      for (int ni = 0; ni < 4; ++ni) {
        int cl = wn + ni * 16 + g * 4;   // dd-local quad base
        int tl = wm + mi * 16 + c;       // token-local
        #pragma unroll
        for (int r = 0; r < 4; ++r)
          T[(cl + r) * 132 + tl] = (bf16_t)acc[mi][ni][r];
      }
    __syncthreads();
    const int bb = m0 >> 11, nn0 = m0 & 2047;
    #pragma unroll
    for (int p = 0; p < 8; ++p) {
      int q8 = p * 256 + tid;            // 0..2047 bf16x8 chunks
      int dl = q8 >> 4, t8 = (q8 & 15) * 8;
      bf16x8 o = *reinterpret_cast<const bf16x8*>(&T[dl * 132 + t8]);
      int ddb = n0 - 1024 + dl;
      int hh = ddb >> 6, ddh = ddb & 63;
      *reinterpret_cast<bf16x8*>(
          &vtb[((size_t)(bb * H_N + hh) * DH + ddh) * N_TOK + nn0 + t8]) = o;
    }
  }
}

// ---------------- GEMM2: out projection, 64x128 tile (2 blocks/CU) ----------------
__global__ __launch_bounds__(256) void gemm_out_kernel(
    const bf16_t* __restrict__ A, const bf16_t* __restrict__ Bt,
    float* __restrict__ outF, const float* __restrict__ bias) {
  __shared__ bf16_t As[64 * 64];
  __shared__ bf16_t Bs[128 * 64];

  const int tid = threadIdx.x;
  const int lane = tid & 63;
  const int wave = tid >> 6;
  const int g = lane >> 4, c = lane & 15;
  const int wm = (wave >> 1) * 32, wn = (wave & 1) * 64;
  const int m0 = blockIdx.x * 64, n0 = blockIdx.y * 128;

  f32x4 acc[2][4] = {};

  for (int k0 = 0; k0 < DIM; k0 += 64) {
    __syncthreads();
    #pragma unroll
    for (int i = 0; i < 2; ++i) {
      int blk = i * 256 + tid;
      int row = blk >> 3;
      int cb = (blk & 7) ^ (row & 7);
      int base = (i * 256 + wave * 64) * 8;
      GLD_LDS16(A + (size_t)(m0 + row) * DIM + k0 + cb * 8, &As[base]);
    }
    #pragma unroll
    for (int i = 0; i < 4; ++i) {
      int blk = i * 256 + tid;
      int row = blk >> 3;
      int cb = (blk & 7) ^ (row & 7);
      int base = (i * 256 + wave * 64) * 8;
      GLD_LDS16(Bt + (size_t)(n0 + row) * DIM + k0 + cb * 8, &Bs[base]);
    }
    __syncthreads();
    __builtin_amdgcn_s_setprio(1);
    #pragma unroll
    for (int ks = 0; ks < 2; ++ks) {
      bf16x8 af[2], bfr[4];
      #pragma unroll
      for (int i = 0; i < 2; ++i)
        af[i] = *reinterpret_cast<const bf16x8*>(
            &As[(wm + i * 16 + c) * 64 + (((ks * 4 + g) ^ (c & 7)) * 8)]);
      #pragma unroll
      for (int i = 0; i < 4; ++i)
        bfr[i] = *reinterpret_cast<const bf16x8*>(
            &Bs[(wn + i * 16 + c) * 64 + (((ks * 4 + g) ^ (c & 7)) * 8)]);
      #pragma unroll
      for (int mi = 0; mi < 2; ++mi)
        #pragma unroll
        for (int ni = 0; ni < 4; ++ni)
          acc[mi][ni] = __builtin_amdgcn_mfma_f32_16x16x32_bf16(
              af[mi], bfr[ni], acc[mi][ni], 0, 0, 0);
    }
    __builtin_amdgcn_s_setprio(0);
  }

  #pragma unroll
  for (int mi = 0; mi < 2; ++mi) {
    #pragma unroll
    for (int ni = 0; ni < 4; ++ni) {
      int colg = n0 + wn + ni * 16 + c;
      #pragma unroll
      for (int r = 0; r < 4; ++r) {
        int rowg = m0 + wm + mi * 16 + g * 4 + r;
        outF[(size_t)rowg * DIM + colg] = acc[mi][ni][r] + bias[colg];
      }
    }
  }
}

// ---------------- flash attention (roles swapped: attQ=K_proj, attK=Q_proj) ----------------
// R14/R11 proven config: 32x32x16 MFMA, split-KV (waves 0-3 tokens [0,1024), waves
// 4-7 [1024,2048), same 128 rows; partials merged via LDS -- valid because no-max
// softmax partials add). K/V double-buffered per group (KVBLK=64). P in registers
// (inline cvt_pk + permlane32_swap). V reads inline in PV (hoisting spills -- R13
// lesson). L via VALU partials. 4 waves/SIMD. XCD-clustered heads.
__global__ __launch_bounds__(512, 4) void attn_kernel(
    const bf16_t* __restrict__ Qproj, const bf16_t* __restrict__ Kproj,
    const bf16_t* __restrict__ Vt, bf16_t* __restrict__ att_out) {
  // 512 blocks = 8 XCDs x 64; each XCD owns 4 (b,h) heads (K+V 2MB fits 4MB L2)
  const int glin = blockIdx.x;
  const int xcd = glin & 7;
  const int jj = glin >> 3;
  const int hb = xcd * 4 + (jj >> 4);
  const int rb = jj & 15;
  const int h = hb & 7, b = hb >> 3;

  const size_t hbo = (size_t)(b * H_N + h);
  const bf16_t* Aq = Kproj + hbo * N_TOK * DH;       // att queries (pre-scaled)
  const bf16_t* Ak = Qproj + hbo * N_TOK * DH;       // att keys
  const bf16_t* Av = Vt + hbo * (size_t)(DH * N_TOK);// V^T [d][n]

  const int tid = threadIdx.x, lane = tid & 63, wave = tid >> 6;
  const int nl = lane & 31;        // lane's att-row (n) within the wave's 32
  const int hf = lane >> 5;        // half-wave
  const int grp = wave >> 2;       // KV-half owner
  const int gw = wave & 3;         // wave within group
  const int r0 = rb * 128, wr0 = gw * 32;
  const int kv0 = grp * 1024;

  // LDS: per group 32KB = sK[2][64*64] + sV[2][64*64]; merge buffer aliases all of it
  __shared__ __align__(16) char smem[65536];
  bf16_t* sKg = (bf16_t*)(smem + grp * 32768);
  bf16_t* sVg = (bf16_t*)(smem + grp * 32768 + 16384);

  // Q fragments (B operand): col n = nl, k(d) = ks*16 + hf*8 + j
  bf16x8 qreg[4];
  #pragma unroll
  for (int ks = 0; ks < 4; ++ks)
    qreg[ks] = *reinterpret_cast<const bf16x8*>(
        &Aq[(size_t)(r0 + wr0 + nl) * DH + ks * 16 + hf * 8]);

  f32x16 accO0 = {}, accO1 = {};   // O^T cols n=nl, d-rows vi*32 + crow
  float Lp[4] = {};                // L partials (static-indexed)

  const int gtid = tid & 255;      // thread id within group
  auto stage = [&](int buf, int j0) {
    #pragma unroll
    for (int i = 0; i < 2; ++i) {
      int idx = i * 256 + gtid;                 // 16B-block 0..511
      int row = idx >> 3;
      int cb = (idx & 7) ^ (row & 7);
      int base = buf * 4096 + (i * 256 + gw * 64) * 8;  // wave-uniform base (elems)
      GLD_LDS16(Ak + (size_t)(j0 + row) * DH + cb * 8, sKg + base);
      GLD_LDS16(Av + (size_t)row * N_TOK + j0 + cb * 8, sVg + base);
    }
  };

  stage(0, kv0);
  __syncthreads();

  constexpr int NT = 16;   // 1024 tokens / 64 per group
  for (int t = 0; t < NT; ++t) {
    if (t + 1 < NT) stage((t + 1) & 1, kv0 + (t + 1) * 64);
    const bf16_t* bK = sKg + (t & 1) * 4096;
    const bf16_t* bV = sVg + (t & 1) * 4096;

    // ---- QK^T: aT[mi] col n=nl, token m = mi*32 + (reg&3)+8*(reg>>2)+4*hf ----
    f32x16 aT[2] = {};
    __builtin_amdgcn_s_setprio(1);
    #pragma unroll
    for (int ks = 0; ks < 4; ++ks) {
      #pragma unroll
      for (int mi = 0; mi < 2; ++mi) {
        int rowt = mi * 32 + nl;
        bf16x8 ak = *reinterpret_cast<const bf16x8*>(
            &bK[rowt * 64 + (((ks * 2 + hf) ^ (rowt & 7)) * 8)]);
        aT[mi] = __builtin_amdgcn_mfma_f32_32x32x16_bf16(
            ak, qreg[ks], aT[mi], 0, 0, 0);
      }
    }
    __builtin_amdgcn_s_setprio(0);

    // ---- softmax: exp2 in place; 4 independent L partials ----
    #pragma unroll
    for (int r = 0; r < 16; ++r) {
      float p0 = fexp2(aT[0][r]); aT[0][r] = p0;
      float p1 = fexp2(aT[1][r]); aT[1][r] = p1;
      Lp[r & 3] += p0 + p1;
    }

    // ---- pack: P -> bf16 pairs, halves exchanged across lane 32 ----
    i32x4 pk[4];
    #pragma unroll
    for (int ks = 0; ks < 4; ++ks) {
      const int mi = ks >> 1, base = (ks & 1) * 8;
      int a0 = cvtpk_bf16(aT[mi][base + 0], aT[mi][base + 1]);
      int b0 = cvtpk_bf16(aT[mi][base + 4], aT[mi][base + 5]);
      int a1 = cvtpk_bf16(aT[mi][base + 2], aT[mi][base + 3]);
      int b1 = cvtpk_bf16(aT[mi][base + 6], aT[mi][base + 7]);
      permswap32(a0, b0);
      permswap32(a1, b1);
      pk[ks].x = a0; pk[ks].y = a1; pk[ks].z = b0; pk[ks].w = b1;
    }

    // ---- PV: O^T += V^T @ P (V reads inline; compiler schedules) ----
    __builtin_amdgcn_s_setprio(1);
    #pragma unroll
    for (int ks = 0; ks < 4; ++ks) {
      bf16x8 pfrag = __builtin_bit_cast(bf16x8, pk[ks]);
      int rv0 = nl, rv1 = 32 + nl;
      bf16x8 av0 = *reinterpret_cast<const bf16x8*>(
          &bV[rv0 * 64 + (((ks * 2 + hf) ^ (rv0 & 7)) * 8)]);
      bf16x8 av1 = *reinterpret_cast<const bf16x8*>(
          &bV[rv1 * 64 + (((ks * 2 + hf) ^ (rv1 & 7)) * 8)]);
      accO0 = __builtin_amdgcn_mfma_f32_32x32x16_bf16(av0, pfrag, accO0, 0, 0, 0);
      accO1 = __builtin_amdgcn_mfma_f32_32x32x16_bf16(av1, pfrag, accO1, 0, 0, 0);
    }
    __builtin_amdgcn_s_setprio(0);

    __syncthreads();   // drains vmcnt(0): prefetch landed; gates buffer swap
  }

  // ---- merge: group 1 writes partials to LDS; group 0 combines + stores ----
  float Lsum = (Lp[0] + Lp[1]) + (Lp[2] + Lp[3]);
  float* mb = (float*)smem;   // [gw][lane][37] f32 stride-37 (odd: conflict-free)
  const int moff = (gw * 64 + lane) * 37;
  if (grp == 1) {
    #pragma unroll
    for (int r = 0; r < 16; ++r) {
      mb[moff + r] = accO0[r];
      mb[moff + 16 + r] = accO1[r];
    }
    mb[moff + 32] = Lsum;
  }
  __syncthreads();
  if (grp == 0) {
    #pragma unroll
    for (int r = 0; r < 16; ++r) {
      accO0[r] += mb[moff + r];
      accO1[r] += mb[moff + 16 + r];
    }
    float l = Lsum + mb[moff + 32];
    l += __shfl_xor(l, 32);
    float invL = 1.0f / l;
    const int nrow = r0 + wr0 + nl;
    #pragma unroll
    for (int q = 0; q < 4; ++q) {
      int d0a = 8 * q + 4 * hf;
      bf16x4v o;
      o.x = (bf16_t)(accO0[4 * q + 0] * invL);
      o.y = (bf16_t)(accO0[4 * q + 1] * invL);
      o.z = (bf16_t)(accO0[4 * q + 2] * invL);
      o.w = (bf16_t)(accO0[4 * q + 3] * invL);
      *reinterpret_cast<bf16x4v*>(
          &att_out[((size_t)(b * N_TOK) + nrow) * INNER + h * DH + d0a]) = o;
      bf16x4v o2;
      o2.x = (bf16_t)(accO1[4 * q + 0] * invL);
      o2.y = (bf16_t)(accO1[4 * q + 1] * invL);
      o2.z = (bf16_t)(accO1[4 * q + 2] * invL);
      o2.w = (bf16_t)(accO1[4 * q + 3] * invL);
      *reinterpret_cast<bf16x4v*>(
          &att_out[((size_t)(b * N_TOK) + nrow) * INNER + h * DH + 32 + d0a]) = o2;
    }
  }
}

// ---------------- launch ----------------

extern "C" void kernel_launch(void* const* d_in, const int* in_sizes, int n_in,
                              void* d_out, int out_size, void* d_ws, size_t ws_size,
                              hipStream_t stream) {
  const float* X    = (const float*)d_in[0];
  const float* Wqkv = (const float*)d_in[1];
  const float* Wout = (const float*)d_in[2];
  const float* bout = (const float*)d_in[3];
  float* out = (float*)d_out;

  char* ws = (char*)d_ws;
  bf16_t* WqkvT = (bf16_t*)(ws + 8388608);       //  1.5MB
  bf16_t* WoutT = (bf16_t*)(ws + 9961472);       //  0.5MB
  bf16_t* Qb    = (bf16_t*)(ws + 10485760);      //  8 MB  [B][H][N][64]
  bf16_t* Kb    = (bf16_t*)(ws + 18874368);      //  8 MB  (pre-scaled by K_FOLD)
  bf16_t* Vtb   = (bf16_t*)(ws + 27262976);      //  8 MB  V^T [B][H][64][N]
  bf16_t* AttO  = (bf16_t*)(ws + 35651584);      //  8 MB

  prep_kernel<<<dim3(256), 256, 0, stream>>>(Wqkv, WqkvT, Wout, WoutT);

  dim3 g1(M_ROWS / 128, NQKV / 128);
  gemm_qkv_kernel<<<g1, 256, 0, stream>>>(X, WqkvT, Qb, Kb, Vtb);

  attn_kernel<<<dim3(512), 512, 0, stream>>>(Qb, Kb, Vtb, AttO);

  dim3 g3(M_ROWS / 64, DIM / 128);
  gemm_out_kernel<<<g3, 256, 0, stream>>>(AttO, WoutT, out, bout);
}

// Round 19
// 79.366 us; speedup vs baseline: 1.1483x; 1.1483x over previous
//
#include <hip/hip_runtime.h>
#include <hip/hip_bf16.h>

typedef __bf16 bf16_t;
typedef bf16_t bf16x8 __attribute__((ext_vector_type(8)));
typedef bf16_t bf16x4v __attribute__((ext_vector_type(4)));
typedef float f32x4 __attribute__((ext_vector_type(4)));
typedef float f32x16 __attribute__((ext_vector_type(16)));
typedef int i32x4 __attribute__((ext_vector_type(4)));

#define B_SZ 4
#define N_TOK 2048
#define DIM 512
#define H_N 8
#define DH 64
#define INNER 512
#define M_ROWS 8192
#define NQKV 1536
#define K_FOLD 0.18033688011112042f  // 0.125 * log2(e): softmax in exp2 domain

#define GLD_LDS16(gp, lp)                                          \
  __builtin_amdgcn_global_load_lds(                                \
      (const __attribute__((address_space(1))) void*)(gp),         \
      (__attribute__((address_space(3))) void*)(lp), 16, 0, 0)

// raw v_exp_f32: inputs bounded (|x| < ~14), no denormal concerns for softmax
__device__ __forceinline__ float fexp2(float x) {
#if __has_builtin(__builtin_amdgcn_exp2f)
  return __builtin_amdgcn_exp2f(x);
#else
  float r;
  asm volatile("v_exp_f32 %0, %1\n\ts_nop 1" : "=v"(r) : "v"(x));
  return r;
#endif
}

// pack two f32 -> one u32 holding (bf16(lo) | bf16(hi)<<16)
__device__ __forceinline__ int cvtpk_bf16(float lo, float hi) {
  int r;
  asm("v_cvt_pk_bf16_f32 %0, %1, %2" : "=v"(r) : "v"(lo), "v"(hi));
  return r;
}

// swap a's upper-32-lane half with b's lower-32-lane half (in place)
__device__ __forceinline__ void permswap32(int& a, int& b) {
  asm volatile("v_permlane32_swap_b32 %0, %1" : "+v"(a), "+v"(b));
}

// ---------------- fused prep ----------------
// blocks [0,2048): X f32->bf16, 32B-read/16B-write per thread (coalesced)
// blocks [2048,2240): Wqkv 64x64 LDS-tiled transpose (coalesced both sides)
// blocks [2240,2304): Wout  64x64 LDS-tiled transpose
__global__ __launch_bounds__(256) void prep_kernel(
    const float* __restrict__ X, bf16_t* __restrict__ Xb,
    const float* __restrict__ Wqkv, bf16_t* __restrict__ WqkvT,
    const float* __restrict__ Wout, bf16_t* __restrict__ WoutT) {
  __shared__ float t[64][65];   // pad-65: column reads are 2-way (free)
  const int bid = blockIdx.x, tid = threadIdx.x;

  if (bid < 2048) {
    int i = bid * 256 + tid;    // 0..524287 = (8192*512)/8
    float4 f0 = reinterpret_cast<const float4*>(X)[2 * i];
    float4 f1 = reinterpret_cast<const float4*>(X)[2 * i + 1];
    bf16x8 o;
    o[0] = (bf16_t)f0.x; o[1] = (bf16_t)f0.y; o[2] = (bf16_t)f0.z; o[3] = (bf16_t)f0.w;
    o[4] = (bf16_t)f1.x; o[5] = (bf16_t)f1.y; o[6] = (bf16_t)f1.z; o[7] = (bf16_t)f1.w;
    reinterpret_cast<bf16x8*>(Xb)[i] = o;
    return;
  }

  int tb = bid - 2048;
  const float* src;
  bf16_t* dst;
  int C, r0, c0;
  if (tb < 192) {               // Wqkv: 512 x 1536, tiles 8 x 24
    src = Wqkv; dst = WqkvT; C = NQKV;
    r0 = (tb / 24) * 64; c0 = (tb % 24) * 64;
  } else {                      // Wout: 512 x 512, tiles 8 x 8
    tb -= 192;
    src = Wout; dst = WoutT; C = DIM;
    r0 = (tb >> 3) * 64; c0 = (tb & 7) * 64;
  }

  #pragma unroll
  for (int p = 0; p < 4; ++p) {
    int idx = p * 256 + tid;          // 0..1023 float4 slots
    int tr = idx >> 4, tc = (idx & 15) * 4;
    float4 v = *reinterpret_cast<const float4*>(&src[(size_t)(r0 + tr) * C + c0 + tc]);
    t[tr][tc] = v.x; t[tr][tc + 1] = v.y; t[tr][tc + 2] = v.z; t[tr][tc + 3] = v.w;
  }
  __syncthreads();
  #pragma unroll
  for (int p = 0; p < 2; ++p) {
    int idx = p * 256 + tid;          // 0..511 bf16x8 slots
    int d = idx >> 3, j8 = idx & 7;   // d = src col = dst row
    bf16x8 o;
    #pragma unroll
    for (int q = 0; q < 8; ++q) o[q] = (bf16_t)t[j8 * 8 + q][d];
    *reinterpret_cast<bf16x8*>(&dst[(size_t)(c0 + d) * 512 + r0 + j8 * 8]) = o;
  }
}

// ---------------- GEMM1: qkv projection (R14 config) ----------------
// q -> qb, k*K_FOLD -> kb ([B][H][N][64]); v -> V^T [B][H][64][N]
__global__ __launch_bounds__(256) void gemm_qkv_kernel(
    const bf16_t* __restrict__ A, const bf16_t* __restrict__ Bt, int K,
    bf16_t* __restrict__ qb, bf16_t* __restrict__ kb, bf16_t* __restrict__ vtb) {
  __shared__ bf16_t As[128 * 64];
  __shared__ bf16_t Bs[128 * 64];

  const int tid = threadIdx.x;
  const int lane = tid & 63;
  const int wave = tid >> 6;
  const int g = lane >> 4, c = lane & 15;
  const int wm = (wave >> 1) * 64, wn = (wave & 1) * 64;
  const int m0 = blockIdx.x * 128, n0 = blockIdx.y * 128;

  f32x4 acc[4][4] = {};

  for (int k0 = 0; k0 < K; k0 += 64) {
    __syncthreads();
    #pragma unroll
    for (int i = 0; i < 4; ++i) {
      int blk = i * 256 + tid;
      int row = blk >> 3;
      int cb = (blk & 7) ^ (row & 7);
      int base = (i * 256 + wave * 64) * 8;
      GLD_LDS16(A + (size_t)(m0 + row) * K + k0 + cb * 8, &As[base]);
      GLD_LDS16(Bt + (size_t)(n0 + row) * K + k0 + cb * 8, &Bs[base]);
    }
    __syncthreads();
    __builtin_amdgcn_s_setprio(1);
    #pragma unroll
    for (int ks = 0; ks < 2; ++ks) {
      bf16x8 af[4], bfr[4];
      #pragma unroll
      for (int i = 0; i < 4; ++i) {
        af[i] = *reinterpret_cast<const bf16x8*>(
            &As[(wm + i * 16 + c) * 64 + (((ks * 4 + g) ^ (c & 7)) * 8)]);
        bfr[i] = *reinterpret_cast<const bf16x8*>(
            &Bs[(wn + i * 16 + c) * 64 + (((ks * 4 + g) ^ (c & 7)) * 8)]);
      }
      #pragma unroll
      for (int mi = 0; mi < 4; ++mi)
        #pragma unroll
        for (int ni = 0; ni < 4; ++ni)
          acc[mi][ni] = __builtin_amdgcn_mfma_f32_16x16x32_bf16(
              af[mi], bfr[ni], acc[mi][ni], 0, 0, 0);
    }
    __builtin_amdgcn_s_setprio(0);
  }

  #pragma unroll
  for (int mi = 0; mi < 4; ++mi) {
    #pragma unroll
    for (int ni = 0; ni < 4; ++ni) {
      int colg = n0 + wn + ni * 16 + c;
      int s = colg >> 9;
      int hh = (colg >> 6) & 7, dd = colg & 63;
      int rowg0 = m0 + wm + mi * 16 + g * 4;
      int bb = rowg0 >> 11, nn = rowg0 & 2047;
      if (s == 2) {
        bf16x4v pk;
        pk.x = (bf16_t)acc[mi][ni][0];
        pk.y = (bf16_t)acc[mi][ni][1];
        pk.z = (bf16_t)acc[mi][ni][2];
        pk.w = (bf16_t)acc[mi][ni][3];
        *reinterpret_cast<bf16x4v*>(
            &vtb[(((size_t)(bb * H_N + hh)) * DH + dd) * N_TOK + nn]) = pk;
      } else {
        float sc = (s == 1) ? K_FOLD : 1.0f;
        bf16_t* dst = (s == 0) ? qb : kb;
        #pragma unroll
        for (int r = 0; r < 4; ++r)
          dst[(((size_t)(bb * H_N + hh)) * N_TOK + nn + r) * DH + dd] =
              (bf16_t)(acc[mi][ni][r] * sc);
      }
    }
  }
}

// ---------------- GEMM2: out projection, 64x128 tile (2 blocks/CU) ----------------
__global__ __launch_bounds__(256) void gemm_out_kernel(
    const bf16_t* __restrict__ A, const bf16_t* __restrict__ Bt,
    float* __restrict__ outF, const float* __restrict__ bias) {
  __shared__ bf16_t As[64 * 64];
  __shared__ bf16_t Bs[128 * 64];

  const int tid = threadIdx.x;
  const int lane = tid & 63;
  const int wave = tid >> 6;
  const int g = lane >> 4, c = lane & 15;
  const int wm = (wave >> 1) * 32, wn = (wave & 1) * 64;
  const int m0 = blockIdx.x * 64, n0 = blockIdx.y * 128;

  f32x4 acc[2][4] = {};

  for (int k0 = 0; k0 < DIM; k0 += 64) {
    __syncthreads();
    #pragma unroll
    for (int i = 0; i < 2; ++i) {
      int blk = i * 256 + tid;
      int row = blk >> 3;
      int cb = (blk & 7) ^ (row & 7);
      int base = (i * 256 + wave * 64) * 8;
      GLD_LDS16(A + (size_t)(m0 + row) * DIM + k0 + cb * 8, &As[base]);
    }
    #pragma unroll
    for (int i = 0; i < 4; ++i) {
      int blk = i * 256 + tid;
      int row = blk >> 3;
      int cb = (blk & 7) ^ (row & 7);
      int base = (i * 256 + wave * 64) * 8;
      GLD_LDS16(Bt + (size_t)(n0 + row) * DIM + k0 + cb * 8, &Bs[base]);
    }
    __syncthreads();
    __builtin_amdgcn_s_setprio(1);
    #pragma unroll
    for (int ks = 0; ks < 2; ++ks) {
      bf16x8 af[2], bfr[4];
      #pragma unroll
      for (int i = 0; i < 2; ++i)
        af[i] = *reinterpret_cast<const bf16x8*>(
            &As[(wm + i * 16 + c) * 64 + (((ks * 4 + g) ^ (c & 7)) * 8)]);
      #pragma unroll
      for (int i = 0; i < 4; ++i)
        bfr[i] = *reinterpret_cast<const bf16x8*>(
            &Bs[(wn + i * 16 + c) * 64 + (((ks * 4 + g) ^ (c & 7)) * 8)]);
      #pragma unroll
      for (int mi = 0; mi < 2; ++mi)
        #pragma unroll
        for (int ni = 0; ni < 4; ++ni)
          acc[mi][ni] = __builtin_amdgcn_mfma_f32_16x16x32_bf16(
              af[mi], bfr[ni], acc[mi][ni], 0, 0, 0);
    }
    __builtin_amdgcn_s_setprio(0);
  }

  #pragma unroll
  for (int mi = 0; mi < 2; ++mi) {
    #pragma unroll
    for (int ni = 0; ni < 4; ++ni) {
      int colg = n0 + wn + ni * 16 + c;
      #pragma unroll
      for (int r = 0; r < 4; ++r) {
        int rowg = m0 + wm + mi * 16 + g * 4 + r;
        outF[(size_t)rowg * DIM + colg] = acc[mi][ni][r] + bias[colg];
      }
    }
  }
}

// ---------------- flash attention (roles swapped: attQ=K_proj, attK=Q_proj) ----------------
// R14/R11 proven config: 32x32x16 MFMA, split-KV (waves 0-3 tokens [0,1024), waves
// 4-7 [1024,2048), same 128 rows; partials merged via LDS -- valid because no-max
// softmax partials add). K/V double-buffered per group (KVBLK=64). P in registers
// (inline cvt_pk + permlane32_swap). V reads inline in PV (hoisting spills -- R13
// lesson). L via VALU partials. 4 waves/SIMD. XCD-clustered heads.
__global__ __launch_bounds__(512, 4) void attn_kernel(
    const bf16_t* __restrict__ Qproj, const bf16_t* __restrict__ Kproj,
    const bf16_t* __restrict__ Vt, bf16_t* __restrict__ att_out) {
  // 512 blocks = 8 XCDs x 64; each XCD owns 4 (b,h) heads (K+V 2MB fits 4MB L2)
  const int glin = blockIdx.x;
  const int xcd = glin & 7;
  const int jj = glin >> 3;
  const int hb = xcd * 4 + (jj >> 4);
  const int rb = jj & 15;
  const int h = hb & 7, b = hb >> 3;

  const size_t hbo = (size_t)(b * H_N + h);
  const bf16_t* Aq = Kproj + hbo * N_TOK * DH;       // att queries (pre-scaled)
  const bf16_t* Ak = Qproj + hbo * N_TOK * DH;       // att keys
  const bf16_t* Av = Vt + hbo * (size_t)(DH * N_TOK);// V^T [d][n]

  const int tid = threadIdx.x, lane = tid & 63, wave = tid >> 6;
  const int nl = lane & 31;        // lane's att-row (n) within the wave's 32
  const int hf = lane >> 5;        // half-wave
  const int grp = wave >> 2;       // KV-half owner
  const int gw = wave & 3;         // wave within group
  const int r0 = rb * 128, wr0 = gw * 32;
  const int kv0 = grp * 1024;

  // LDS: per group 32KB = sK[2][64*64] + sV[2][64*64]; merge buffer aliases all of it
  __shared__ __align__(16) char smem[65536];
  bf16_t* sKg = (bf16_t*)(smem + grp * 32768);
  bf16_t* sVg = (bf16_t*)(smem + grp * 32768 + 16384);

  // Q fragments (B operand): col n = nl, k(d) = ks*16 + hf*8 + j
  bf16x8 qreg[4];
  #pragma unroll
  for (int ks = 0; ks < 4; ++ks)
    qreg[ks] = *reinterpret_cast<const bf16x8*>(
        &Aq[(size_t)(r0 + wr0 + nl) * DH + ks * 16 + hf * 8]);

  f32x16 accO0 = {}, accO1 = {};   // O^T cols n=nl, d-rows vi*32 + crow
  float Lp[4] = {};                // L partials (static-indexed)

  const int gtid = tid & 255;      // thread id within group
  auto stage = [&](int buf, int j0) {
    #pragma unroll
    for (int i = 0; i < 2; ++i) {
      int idx = i * 256 + gtid;                 // 16B-block 0..511
      int row = idx >> 3;
      int cb = (idx & 7) ^ (row & 7);
      int base = buf * 4096 + (i * 256 + gw * 64) * 8;  // wave-uniform base (elems)
      GLD_LDS16(Ak + (size_t)(j0 + row) * DH + cb * 8, sKg + base);
      GLD_LDS16(Av + (size_t)row * N_TOK + j0 + cb * 8, sVg + base);
    }
  };

  stage(0, kv0);
  __syncthreads();

  constexpr int NT = 16;   // 1024 tokens / 64 per group
  for (int t = 0; t < NT; ++t) {
    if (t + 1 < NT) stage((t + 1) & 1, kv0 + (t + 1) * 64);
    const bf16_t* bK = sKg + (t & 1) * 4096;
    const bf16_t* bV = sVg + (t & 1) * 4096;

    // ---- QK^T: aT[mi] col n=nl, token m = mi*32 + (reg&3)+8*(reg>>2)+4*hf ----
    f32x16 aT[2] = {};
    __builtin_amdgcn_s_setprio(1);
    #pragma unroll
    for (int ks = 0; ks < 4; ++ks) {
      #pragma unroll
      for (int mi = 0; mi < 2; ++mi) {
        int rowt = mi * 32 + nl;
        bf16x8 ak = *reinterpret_cast<const bf16x8*>(
            &bK[rowt * 64 + (((ks * 2 + hf) ^ (rowt & 7)) * 8)]);
        aT[mi] = __builtin_amdgcn_mfma_f32_32x32x16_bf16(
            ak, qreg[ks], aT[mi], 0, 0, 0);
      }
    }
    __builtin_amdgcn_s_setprio(0);

    // ---- softmax: exp2 in place; 4 independent L partials ----
    #pragma unroll
    for (int r = 0; r < 16; ++r) {
      float p0 = fexp2(aT[0][r]); aT[0][r] = p0;
      float p1 = fexp2(aT[1][r]); aT[1][r] = p1;
      Lp[r & 3] += p0 + p1;
    }

    // ---- pack: P -> bf16 pairs, halves exchanged across lane 32 ----
    i32x4 pk[4];
    #pragma unroll
    for (int ks = 0; ks < 4; ++ks) {
      const int mi = ks >> 1, base = (ks & 1) * 8;
      int a0 = cvtpk_bf16(aT[mi][base + 0], aT[mi][base + 1]);
      int b0 = cvtpk_bf16(aT[mi][base + 4], aT[mi][base + 5]);
      int a1 = cvtpk_bf16(aT[mi][base + 2], aT[mi][base + 3]);
      int b1 = cvtpk_bf16(aT[mi][base + 6], aT[mi][base + 7]);
      permswap32(a0, b0);
      permswap32(a1, b1);
      pk[ks].x = a0; pk[ks].y = a1; pk[ks].z = b0; pk[ks].w = b1;
    }

    // ---- PV: O^T += V^T @ P (V reads inline; compiler schedules) ----
    __builtin_amdgcn_s_setprio(1);
    #pragma unroll
    for (int ks = 0; ks < 4; ++ks) {
      bf16x8 pfrag = __builtin_bit_cast(bf16x8, pk[ks]);
      int rv0 = nl, rv1 = 32 + nl;
      bf16x8 av0 = *reinterpret_cast<const bf16x8*>(
          &bV[rv0 * 64 + (((ks * 2 + hf) ^ (rv0 & 7)) * 8)]);
      bf16x8 av1 = *reinterpret_cast<const bf16x8*>(
          &bV[rv1 * 64 + (((ks * 2 + hf) ^ (rv1 & 7)) * 8)]);
      accO0 = __builtin_amdgcn_mfma_f32_32x32x16_bf16(av0, pfrag, accO0, 0, 0, 0);
      accO1 = __builtin_amdgcn_mfma_f32_32x32x16_bf16(av1, pfrag, accO1, 0, 0, 0);
    }
    __builtin_amdgcn_s_setprio(0);

    __syncthreads();   // drains vmcnt(0): prefetch landed; gates buffer swap
  }

  // ---- merge: group 1 writes partials to LDS; group 0 combines + stores ----
  float Lsum = (Lp[0] + Lp[1]) + (Lp[2] + Lp[3]);
  float* mb = (float*)smem;   // [gw][lane][37] f32 stride-37 (odd: conflict-free)
  const int moff = (gw * 64 + lane) * 37;
  if (grp == 1) {
    #pragma unroll
    for (int r = 0; r < 16; ++r) {
      mb[moff + r] = accO0[r];
      mb[moff + 16 + r] = accO1[r];
    }
    mb[moff + 32] = Lsum;
  }
  __syncthreads();
  if (grp == 0) {
    #pragma unroll
    for (int r = 0; r < 16; ++r) {
      accO0[r] += mb[moff + r];
      accO1[r] += mb[moff + 16 + r];
    }
    float l = Lsum + mb[moff + 32];
    l += __shfl_xor(l, 32);
    float invL = 1.0f / l;
    const int nrow = r0 + wr0 + nl;
    #pragma unroll
    for (int q = 0; q < 4; ++q) {
      int d0a = 8 * q + 4 * hf;
      bf16x4v o;
      o.x = (bf16_t)(accO0[4 * q + 0] * invL);
      o.y = (bf16_t)(accO0[4 * q + 1] * invL);
      o.z = (bf16_t)(accO0[4 * q + 2] * invL);
      o.w = (bf16_t)(accO0[4 * q + 3] * invL);
      *reinterpret_cast<bf16x4v*>(
          &att_out[((size_t)(b * N_TOK) + nrow) * INNER + h * DH + d0a]) = o;
      bf16x4v o2;
      o2.x = (bf16_t)(accO1[4 * q + 0] * invL);
      o2.y = (bf16_t)(accO1[4 * q + 1] * invL);
      o2.z = (bf16_t)(accO1[4 * q + 2] * invL);
      o2.w = (bf16_t)(accO1[4 * q + 3] * invL);
      *reinterpret_cast<bf16x4v*>(
          &att_out[((size_t)(b * N_TOK) + nrow) * INNER + h * DH + 32 + d0a]) = o2;
    }
  }
}

// ---------------- launch ----------------

extern "C" void kernel_launch(void* const* d_in, const int* in_sizes, int n_in,
                              void* d_out, int out_size, void* d_ws, size_t ws_size,
                              hipStream_t stream) {
  const float* X    = (const float*)d_in[0];
  const float* Wqkv = (const float*)d_in[1];
  const float* Wout = (const float*)d_in[2];
  const float* bout = (const float*)d_in[3];
  float* out = (float*)d_out;

  char* ws = (char*)d_ws;
  bf16_t* Xb    = (bf16_t*)(ws);                 //  8 MB  X bf16
  bf16_t* WqkvT = (bf16_t*)(ws + 8388608);       //  1.5MB
  bf16_t* WoutT = (bf16_t*)(ws + 9961472);       //  0.5MB
  bf16_t* Qb    = (bf16_t*)(ws + 10485760);      //  8 MB  [B][H][N][64]
  bf16_t* Kb    = (bf16_t*)(ws + 18874368);      //  8 MB  (pre-scaled by K_FOLD)
  bf16_t* Vtb   = (bf16_t*)(ws + 27262976);      //  8 MB  V^T [B][H][64][N]
  bf16_t* AttO  = (bf16_t*)(ws + 35651584);      //  8 MB

  prep_kernel<<<dim3(2304), 256, 0, stream>>>(X, Xb, Wqkv, WqkvT, Wout, WoutT);

  dim3 g1(M_ROWS / 128, NQKV / 128);
  gemm_qkv_kernel<<<g1, 256, 0, stream>>>(Xb, WqkvT, DIM, Qb, Kb, Vtb);

  attn_kernel<<<dim3(512), 512, 0, stream>>>(Qb, Kb, Vtb, AttO);

  dim3 g3(M_ROWS / 64, DIM / 128);
  gemm_out_kernel<<<g3, 256, 0, stream>>>(AttO, WoutT, out, bout);
}